// Round 1
// baseline (941.223 us; speedup 1.0000x reference)
//
#include <hip/hip_runtime.h>

#define NN 80000
#define NE 1280000
#define NG 2000
#define HID 64
#define FIN1 40
constexpr float EPS = 1e-5f;

// ---------------- embed: x0[n][f] = concat(shape_tab, color_tab, pos_tab) ----
__global__ void embed_kernel(const int* __restrict__ sid, const int* __restrict__ cid,
                             const int* __restrict__ pid,
                             const float* __restrict__ stab, const float* __restrict__ ctab,
                             const float* __restrict__ ptab,
                             float* __restrict__ x0) {
    int idx = blockIdx.x * blockDim.x + threadIdx.x;
    if (idx >= NN * FIN1) return;
    int n = idx / FIN1;
    int f = idx - n * FIN1;
    float v;
    if (f < 16)      v = stab[sid[n] * 16 + f];
    else if (f < 32) v = ctab[cid[n] * 16 + (f - 16)];
    else             v = ptab[pid[n] * 8 + (f - 32)];
    x0[idx] = v;
}

// ---------------- deg[d] += 1 per edge ----------------
__global__ void deg_kernel(const int* __restrict__ dst, float* __restrict__ deg) {
    int e = blockIdx.x * blockDim.x + threadIdx.x;
    if (e >= NE) return;
    atomicAdd(&deg[dst[e]], 1.0f);
}

// ---------------- scatter: agg[dst][f] += x[src][f] ----------------
template <int F>
__global__ void scatter_kernel(const int* __restrict__ src, const int* __restrict__ dst,
                               const float* __restrict__ x, float* __restrict__ agg) {
    int idx = blockIdx.x * blockDim.x + threadIdx.x;
    if (idx >= NE * F) return;
    int e = idx / F;
    int f = idx - e * F;
    int s = src[e];
    int d = dst[e];
    atomicAdd(&agg[d * F + f], x[s * F + f]);
}

// ---------------- h[n][:] = (agg[n]/max(deg,1)) @ Wl + b + x[n] @ Wr --------
template <int FIN>
__global__ void sage_linear(const float* __restrict__ x, const float* __restrict__ agg,
                            const float* __restrict__ deg,
                            const float* __restrict__ Wl, const float* __restrict__ Wr,
                            const float* __restrict__ b, float* __restrict__ h) {
    int n = blockIdx.x * blockDim.x + threadIdx.x;
    if (n >= NN) return;
    float acc[HID];
#pragma unroll
    for (int j = 0; j < HID; j++) acc[j] = b[j];
    float inv = 1.0f / fmaxf(deg[n], 1.0f);
    for (int k = 0; k < FIN; k++) {
        float xa = agg[n * FIN + k] * inv;
        float xr = x[n * FIN + k];
        const float* wl = &Wl[k * HID];
        const float* wr = &Wr[k * HID];
#pragma unroll
        for (int j = 0; j < HID; j++) {
            acc[j] = fmaf(xa, wl[j], fmaf(xr, wr[j], acc[j]));
        }
    }
#pragma unroll
    for (int j = 0; j < HID; j++) h[n * HID + j] = acc[j];
}

// ---------------- BN stats: stats[f] = sum, stats[64+f] = sumsq -------------
__global__ void bn_stats(const float* __restrict__ h, float* __restrict__ stats) {
    const int NPB = 512;
    int f = threadIdx.x & 63;
    int r = threadIdx.x >> 6;
    int n0 = blockIdx.x * NPB;
    int nend = min(n0 + NPB, NN);
    float s = 0.f, ss = 0.f;
    for (int n = n0 + r; n < nend; n += 4) {
        float v = h[n * HID + f];
        s += v;
        ss += v * v;
    }
    __shared__ float ls[4][64];
    __shared__ float lss[4][64];
    ls[r][f] = s;
    lss[r][f] = ss;
    __syncthreads();
    if (r == 0) {
        s = ls[0][f] + ls[1][f] + ls[2][f] + ls[3][f];
        ss = lss[0][f] + lss[1][f] + lss[2][f] + lss[3][f];
        atomicAdd(&stats[f], s);
        atomicAdd(&stats[64 + f], ss);
    }
}

// ---------------- BN apply + ReLU (in-place ok) ----------------
__global__ void bn_apply_relu(const float* __restrict__ h, const float* __restrict__ stats,
                              const float* __restrict__ g, const float* __restrict__ be,
                              float* __restrict__ x) {
    int idx = blockIdx.x * blockDim.x + threadIdx.x;
    if (idx >= NN * HID) return;
    int f = idx & 63;
    const float invn = 1.0f / (float)NN;
    float m = stats[f] * invn;
    float var = stats[64 + f] * invn - m * m;
    float sc = g[f] / sqrtf(var + EPS);
    float v = (h[idx] - m) * sc + be[f];
    x[idx] = fmaxf(v, 0.0f);
}

// ---------------- pool: pooled[batch[n]][f] += x[n][f]; cnt[batch[n]] += 1 ---
__global__ void pool_kernel(const float* __restrict__ x, const int* __restrict__ batch,
                            float* __restrict__ pooled, float* __restrict__ cnt) {
    int idx = blockIdx.x * blockDim.x + threadIdx.x;
    if (idx >= NN * HID) return;
    int n = idx >> 6;
    int f = idx & 63;
    int g = batch[n];
    atomicAdd(&pooled[g * HID + f], x[idx]);
    if (f == 0) atomicAdd(&cnt[g], 1.0f);
}

// ---------------- out[g][o] = (pooled[g]/max(cnt,1)) @ Wout + bout ----------
__global__ void out_kernel(const float* __restrict__ pooled, const float* __restrict__ cnt,
                           const float* __restrict__ Wout, const float* __restrict__ bout,
                           float* __restrict__ out) {
    int g = blockIdx.x * blockDim.x + threadIdx.x;
    if (g >= NG) return;
    float inv = 1.0f / fmaxf(cnt[g], 1.0f);
    float a0 = bout[0], a1 = bout[1];
    for (int f = 0; f < HID; f++) {
        float p = pooled[g * HID + f] * inv;
        a0 = fmaf(p, Wout[f * 2 + 0], a0);
        a1 = fmaf(p, Wout[f * 2 + 1], a1);
    }
    out[g * 2 + 0] = a0;
    out[g * 2 + 1] = a1;
}

extern "C" void kernel_launch(void* const* d_in, const int* in_sizes, int n_in,
                              void* d_out, int out_size, void* d_ws, size_t ws_size,
                              hipStream_t stream) {
    const int* sid = (const int*)d_in[0];
    const int* cid = (const int*)d_in[1];
    const int* pid = (const int*)d_in[2];
    const int* ei = (const int*)d_in[3];
    const int* batch = (const int*)d_in[4];
    const float* stab = (const float*)d_in[6];
    const float* ctab = (const float*)d_in[7];
    const float* ptab = (const float*)d_in[8];
    const float* W1l = (const float*)d_in[9];
    const float* b1 = (const float*)d_in[10];
    const float* W1r = (const float*)d_in[11];
    const float* g1 = (const float*)d_in[12];
    const float* be1 = (const float*)d_in[13];
    const float* W2l = (const float*)d_in[14];
    const float* b2 = (const float*)d_in[15];
    const float* W2r = (const float*)d_in[16];
    const float* g2 = (const float*)d_in[17];
    const float* be2 = (const float*)d_in[18];
    const float* Wout = (const float*)d_in[19];
    const float* bout = (const float*)d_in[20];

    const int* src = ei;
    const int* dst = ei + NE;

    float* ws = (float*)d_ws;
    float* x0 = ws;                                // NN*40
    float* agg = x0 + (size_t)NN * FIN1;           // NN*64
    float* hbuf = agg + (size_t)NN * HID;          // NN*64
    float* deg = hbuf + (size_t)NN * HID;          // NN
    float* stats = deg + NN;                       // 256 (both layers)
    float* pooled = stats + 256;                   // NG*64
    float* cnt = pooled + (size_t)NG * HID;        // NG

    // zero the accumulation buffers (harness does NOT re-poison between replays)
    hipMemsetAsync(deg, 0, NN * sizeof(float), stream);
    hipMemsetAsync(agg, 0, (size_t)NN * FIN1 * sizeof(float), stream);
    hipMemsetAsync(stats, 0, 256 * sizeof(float), stream);
    hipMemsetAsync(pooled, 0, ((size_t)NG * HID + NG) * sizeof(float), stream);

    const int B = 256;
    // features
    embed_kernel<<<(NN * FIN1 + B - 1) / B, B, 0, stream>>>(sid, cid, pid, stab, ctab, ptab, x0);
    // degree (shared across both layers)
    deg_kernel<<<(NE + B - 1) / B, B, 0, stream>>>(dst, deg);

    // ---- layer 1 ----
    scatter_kernel<FIN1><<<(NE * FIN1 + B - 1) / B, B, 0, stream>>>(src, dst, x0, agg);
    sage_linear<FIN1><<<(NN + B - 1) / B, B, 0, stream>>>(x0, agg, deg, W1l, W1r, b1, hbuf);
    bn_stats<<<(NN + 511) / 512, B, 0, stream>>>(hbuf, stats);
    bn_apply_relu<<<(NN * HID + B - 1) / B, B, 0, stream>>>(hbuf, stats, g1, be1, hbuf);

    // ---- layer 2 ----
    hipMemsetAsync(agg, 0, (size_t)NN * HID * sizeof(float), stream);
    scatter_kernel<HID><<<(NE * HID + B - 1) / B, B, 0, stream>>>(src, dst, hbuf, agg);
    sage_linear<HID><<<(NN + B - 1) / B, B, 0, stream>>>(hbuf, agg, deg, W2l, W2r, b2, hbuf);
    bn_stats<<<(NN + 511) / 512, B, 0, stream>>>(hbuf, stats + 128);
    bn_apply_relu<<<(NN * HID + B - 1) / B, B, 0, stream>>>(hbuf, stats + 128, g2, be2, hbuf);

    // ---- pool + head ----
    pool_kernel<<<(NN * HID + B - 1) / B, B, 0, stream>>>(hbuf, batch, pooled, cnt);
    out_kernel<<<(NG + B - 1) / B, B, 0, stream>>>(pooled, cnt, Wout, bout, (float*)d_out);
}

// Round 2
// 802.923 us; speedup vs baseline: 1.1722x; 1.1722x over previous
//
#include <hip/hip_runtime.h>

#define NN 80000
#define NE 1280000
#define NG 2000
#define HID 64
#define FIN1 40
constexpr float EPS = 1e-5f;

// ---------------- embed: x0[n][f] = concat(shape_tab, color_tab, pos_tab) ----
__global__ void embed_kernel(const int* __restrict__ sid, const int* __restrict__ cid,
                             const int* __restrict__ pid,
                             const float* __restrict__ stab, const float* __restrict__ ctab,
                             const float* __restrict__ ptab,
                             float* __restrict__ x0) {
    int idx = blockIdx.x * blockDim.x + threadIdx.x;
    if (idx >= NN * FIN1) return;
    int n = idx / FIN1;
    int f = idx - n * FIN1;
    float v;
    if (f < 16)      v = stab[sid[n] * 16 + f];
    else if (f < 32) v = ctab[cid[n] * 16 + (f - 16)];
    else             v = ptab[pid[n] * 8 + (f - 32)];
    x0[idx] = v;
}

// ---------------- CSR build ----------------
// hist: cursor[d]++ per edge (int atomics, 5MB traffic)
__global__ void deg_hist(const int* __restrict__ dst, int* __restrict__ cursor) {
    int e = blockIdx.x * blockDim.x + threadIdx.x;
    if (e >= NE) return;
    atomicAdd(&cursor[dst[e]], 1);
}

// single-block exclusive scan: reads deg from cursor, writes row_ptr (exclusive
// prefix) and overwrites cursor with the same exclusive prefix (fill cursors).
__global__ void scan_kernel(int* __restrict__ cursor, int* __restrict__ row_ptr) {
    __shared__ int lsum[1024];
    __shared__ int carry;
    int t = threadIdx.x;
    if (t == 0) carry = 0;
    __syncthreads();
    const int PER = 8;
    const int CHUNK = 1024 * PER;
    for (int base = 0; base < NN; base += CHUNK) {
        int v[PER];
        int local = 0;
#pragma unroll
        for (int i = 0; i < PER; i++) {
            int idx = base + t * PER + i;
            v[i] = (idx < NN) ? cursor[idx] : 0;
            local += v[i];
        }
        lsum[t] = local;
        __syncthreads();
        for (int off = 1; off < 1024; off <<= 1) {
            int x = (t >= off) ? lsum[t - off] : 0;
            __syncthreads();
            lsum[t] += x;
            __syncthreads();
        }
        int carry_in = carry;
        int excl = ((t == 0) ? 0 : lsum[t - 1]) + carry_in;
#pragma unroll
        for (int i = 0; i < PER; i++) {
            int idx = base + t * PER + i;
            if (idx < NN) {
                row_ptr[idx] = excl;
                cursor[idx] = excl;
                excl += v[i];
            }
        }
        __syncthreads();
        if (t == 0) carry = carry_in + lsum[1023];
        __syncthreads();
    }
    if (t == 0) row_ptr[NN] = carry;
}

// fill: eidx[cursor[dst[e]]++] = src[e]
__global__ void csr_fill(const int* __restrict__ src, const int* __restrict__ dst,
                         int* __restrict__ cursor, int* __restrict__ eidx) {
    int e = blockIdx.x * blockDim.x + threadIdx.x;
    if (e >= NE) return;
    int pos = atomicAdd(&cursor[dst[e]], 1);
    eidx[pos] = src[e];
}

// ---------------- gather-aggregate: agg[n][f] = sum_{s in N(n)} x[s][f] -----
// one 64-lane wave per node; lane = feature; neighbor ids broadcast via shfl
template <int F>
__global__ void gather_agg(const int* __restrict__ row_ptr, const int* __restrict__ eidx,
                           const float* __restrict__ x, float* __restrict__ agg) {
    int t = blockIdx.x * blockDim.x + threadIdx.x;
    int n = t >> 6;
    int f = t & 63;
    if (n >= NN) return;
    int beg = row_ptr[n];
    int end = row_ptr[n + 1];
    float acc = 0.0f;
    for (int j0 = beg; j0 < end; j0 += 64) {
        int myid = (j0 + f < end) ? eidx[j0 + f] : 0;
        int cnt = min(64, end - j0);
        for (int u = 0; u < cnt; u++) {
            int s = __shfl(myid, u);
            if (f < F) acc += x[(size_t)s * F + f];
        }
    }
    if (f < F) agg[(size_t)n * F + f] = acc;
}

// ---------------- h[n][:] = (agg[n]/max(deg,1)) @ Wl + b + x[n] @ Wr --------
template <int FIN>
__global__ void sage_linear(const float* __restrict__ x, const float* __restrict__ agg,
                            const int* __restrict__ row_ptr,
                            const float* __restrict__ Wl, const float* __restrict__ Wr,
                            const float* __restrict__ b, float* __restrict__ h) {
    int n = blockIdx.x * blockDim.x + threadIdx.x;
    if (n >= NN) return;
    float acc[HID];
#pragma unroll
    for (int j = 0; j < HID; j++) acc[j] = b[j];
    int deg = row_ptr[n + 1] - row_ptr[n];
    float inv = 1.0f / (float)max(deg, 1);
    for (int k = 0; k < FIN; k++) {
        float xa = agg[n * FIN + k] * inv;
        float xr = x[n * FIN + k];
        const float* wl = &Wl[k * HID];
        const float* wr = &Wr[k * HID];
#pragma unroll
        for (int j = 0; j < HID; j++) {
            acc[j] = fmaf(xa, wl[j], fmaf(xr, wr[j], acc[j]));
        }
    }
#pragma unroll
    for (int j = 0; j < HID; j++) h[n * HID + j] = acc[j];
}

// ---------------- BN stats: stats[f] = sum, stats[64+f] = sumsq -------------
__global__ void bn_stats(const float* __restrict__ h, float* __restrict__ stats) {
    const int NPB = 512;
    int f = threadIdx.x & 63;
    int r = threadIdx.x >> 6;
    int n0 = blockIdx.x * NPB;
    int nend = min(n0 + NPB, NN);
    float s = 0.f, ss = 0.f;
    for (int n = n0 + r; n < nend; n += 4) {
        float v = h[n * HID + f];
        s += v;
        ss += v * v;
    }
    __shared__ float ls[4][64];
    __shared__ float lss[4][64];
    ls[r][f] = s;
    lss[r][f] = ss;
    __syncthreads();
    if (r == 0) {
        s = ls[0][f] + ls[1][f] + ls[2][f] + ls[3][f];
        ss = lss[0][f] + lss[1][f] + lss[2][f] + lss[3][f];
        atomicAdd(&stats[f], s);
        atomicAdd(&stats[64 + f], ss);
    }
}

// ---------------- BN apply + ReLU (in-place ok) ----------------
__global__ void bn_apply_relu(const float* __restrict__ h, const float* __restrict__ stats,
                              const float* __restrict__ g, const float* __restrict__ be,
                              float* __restrict__ x) {
    int idx = blockIdx.x * blockDim.x + threadIdx.x;
    if (idx >= NN * HID) return;
    int f = idx & 63;
    const float invn = 1.0f / (float)NN;
    float m = stats[f] * invn;
    float var = stats[64 + f] * invn - m * m;
    float sc = g[f] / sqrtf(var + EPS);
    float v = (h[idx] - m) * sc + be[f];
    x[idx] = fmaxf(v, 0.0f);
}

// ---------------- pool: pooled[batch[n]][f] += x[n][f]; cnt[batch[n]] += 1 ---
__global__ void pool_kernel(const float* __restrict__ x, const int* __restrict__ batch,
                            float* __restrict__ pooled, float* __restrict__ cnt) {
    int idx = blockIdx.x * blockDim.x + threadIdx.x;
    if (idx >= NN * HID) return;
    int n = idx >> 6;
    int f = idx & 63;
    int g = batch[n];
    atomicAdd(&pooled[g * HID + f], x[idx]);
    if (f == 0) atomicAdd(&cnt[g], 1.0f);
}

// ---------------- out[g][o] = (pooled[g]/max(cnt,1)) @ Wout + bout ----------
__global__ void out_kernel(const float* __restrict__ pooled, const float* __restrict__ cnt,
                           const float* __restrict__ Wout, const float* __restrict__ bout,
                           float* __restrict__ out) {
    int g = blockIdx.x * blockDim.x + threadIdx.x;
    if (g >= NG) return;
    float inv = 1.0f / fmaxf(cnt[g], 1.0f);
    float a0 = bout[0], a1 = bout[1];
    for (int f = 0; f < HID; f++) {
        float p = pooled[g * HID + f] * inv;
        a0 = fmaf(p, Wout[f * 2 + 0], a0);
        a1 = fmaf(p, Wout[f * 2 + 1], a1);
    }
    out[g * 2 + 0] = a0;
    out[g * 2 + 1] = a1;
}

extern "C" void kernel_launch(void* const* d_in, const int* in_sizes, int n_in,
                              void* d_out, int out_size, void* d_ws, size_t ws_size,
                              hipStream_t stream) {
    const int* sid = (const int*)d_in[0];
    const int* cid = (const int*)d_in[1];
    const int* pid = (const int*)d_in[2];
    const int* ei = (const int*)d_in[3];
    const int* batch = (const int*)d_in[4];
    const float* stab = (const float*)d_in[6];
    const float* ctab = (const float*)d_in[7];
    const float* ptab = (const float*)d_in[8];
    const float* W1l = (const float*)d_in[9];
    const float* b1 = (const float*)d_in[10];
    const float* W1r = (const float*)d_in[11];
    const float* g1 = (const float*)d_in[12];
    const float* be1 = (const float*)d_in[13];
    const float* W2l = (const float*)d_in[14];
    const float* b2 = (const float*)d_in[15];
    const float* W2r = (const float*)d_in[16];
    const float* g2 = (const float*)d_in[17];
    const float* be2 = (const float*)d_in[18];
    const float* Wout = (const float*)d_in[19];
    const float* bout = (const float*)d_in[20];

    const int* src = ei;
    const int* dst = ei + NE;

    float* ws = (float*)d_ws;
    float* x0 = ws;                                // NN*40 f
    float* agg = x0 + (size_t)NN * FIN1;           // NN*64 f
    float* hbuf = agg + (size_t)NN * HID;          // NN*64 f
    float* stats = hbuf + (size_t)NN * HID;        // 256 f (both layers)
    float* pooled = stats + 256;                   // NG*64 f
    float* cnt = pooled + (size_t)NG * HID;        // NG f
    int* row_ptr = (int*)(cnt + NG);               // NN+1 i
    int* cursor = row_ptr + NN + 1;                // NN i
    int* eidx = cursor + NN;                       // NE i

    // zero the accumulation buffers (harness does NOT re-poison between replays)
    hipMemsetAsync(cursor, 0, NN * sizeof(int), stream);
    hipMemsetAsync(stats, 0, 256 * sizeof(float), stream);
    hipMemsetAsync(pooled, 0, ((size_t)NG * HID + NG) * sizeof(float), stream);

    const int B = 256;
    // features
    embed_kernel<<<(NN * FIN1 + B - 1) / B, B, 0, stream>>>(sid, cid, pid, stab, ctab, ptab, x0);

    // CSR build (shared across both layers)
    deg_hist<<<(NE + B - 1) / B, B, 0, stream>>>(dst, cursor);
    scan_kernel<<<1, 1024, 0, stream>>>(cursor, row_ptr);
    csr_fill<<<(NE + B - 1) / B, B, 0, stream>>>(src, dst, cursor, eidx);

    // ---- layer 1 ----
    gather_agg<FIN1><<<(NN * 64 + B - 1) / B, B, 0, stream>>>(row_ptr, eidx, x0, agg);
    sage_linear<FIN1><<<(NN + B - 1) / B, B, 0, stream>>>(x0, agg, row_ptr, W1l, W1r, b1, hbuf);
    bn_stats<<<(NN + 511) / 512, B, 0, stream>>>(hbuf, stats);
    bn_apply_relu<<<(NN * HID + B - 1) / B, B, 0, stream>>>(hbuf, stats, g1, be1, hbuf);

    // ---- layer 2 ----
    gather_agg<HID><<<(NN * 64 + B - 1) / B, B, 0, stream>>>(row_ptr, eidx, hbuf, agg);
    sage_linear<HID><<<(NN + B - 1) / B, B, 0, stream>>>(hbuf, agg, row_ptr, W2l, W2r, b2, hbuf);
    bn_stats<<<(NN + 511) / 512, B, 0, stream>>>(hbuf, stats + 128);
    bn_apply_relu<<<(NN * HID + B - 1) / B, B, 0, stream>>>(hbuf, stats + 128, g2, be2, hbuf);

    // ---- pool + head ----
    pool_kernel<<<(NN * HID + B - 1) / B, B, 0, stream>>>(hbuf, batch, pooled, cnt);
    out_kernel<<<(NG + B - 1) / B, B, 0, stream>>>(pooled, cnt, Wout, bout, (float*)d_out);
}

// Round 3
// 556.868 us; speedup vs baseline: 1.6902x; 1.4419x over previous
//
#include <hip/hip_runtime.h>

#define NN 80000
#define NE 1280000
#define NG 2000
#define HID 64
#define FIN1 40
#define SCHUNK 512
#define SNB ((NN + SCHUNK - 1) / SCHUNK)   // 157 blocks
constexpr float EPS = 1e-5f;

// ---------------- embed: x0[n][f] = concat(shape_tab, color_tab, pos_tab) ----
__global__ void embed_kernel(const int* __restrict__ sid, const int* __restrict__ cid,
                             const int* __restrict__ pid,
                             const float* __restrict__ stab, const float* __restrict__ ctab,
                             const float* __restrict__ ptab,
                             float* __restrict__ x0) {
    int idx = blockIdx.x * blockDim.x + threadIdx.x;
    if (idx >= NN * FIN1) return;
    int n = idx / FIN1;
    int f = idx - n * FIN1;
    float v;
    if (f < 16)      v = stab[sid[n] * 16 + f];
    else if (f < 32) v = ctab[cid[n] * 16 + (f - 16)];
    else             v = ptab[pid[n] * 8 + (f - 32)];
    x0[idx] = v;
}

// ---------------- CSR build ----------------
__global__ void deg_hist(const int* __restrict__ dst, int* __restrict__ cursor) {
    int e = blockIdx.x * blockDim.x + threadIdx.x;
    if (e >= NE) return;
    atomicAdd(&cursor[dst[e]], 1);
}

// phase A: per-block sums of deg
__global__ void scan_a(const int* __restrict__ cursor, int* __restrict__ bsum) {
    __shared__ int l[SCHUNK];
    int t = threadIdx.x;
    int idx = blockIdx.x * SCHUNK + t;
    l[t] = (idx < NN) ? cursor[idx] : 0;
    __syncthreads();
    for (int off = SCHUNK / 2; off >= 1; off >>= 1) {
        if (t < off) l[t] += l[t + off];
        __syncthreads();
    }
    if (t == 0) bsum[blockIdx.x] = l[0];
}

// phase B: exclusive scan of 157 block sums (single block, 256 threads)
__global__ void scan_b(const int* __restrict__ bsum, int* __restrict__ boffs) {
    __shared__ int l[256];
    int t = threadIdx.x;
    l[t] = (t < SNB) ? bsum[t] : 0;
    __syncthreads();
    for (int off = 1; off < 256; off <<= 1) {
        int v = (t >= off) ? l[t - off] : 0;
        __syncthreads();
        l[t] += v;
        __syncthreads();
    }
    boffs[t] = (t == 0) ? 0 : l[t - 1];
}

// phase C: local exclusive scan + block offset -> row_ptr, cursor
__global__ void scan_c(int* __restrict__ cursor, const int* __restrict__ boffs,
                       int* __restrict__ row_ptr) {
    __shared__ int l[SCHUNK];
    int t = threadIdx.x;
    int idx = blockIdx.x * SCHUNK + t;
    l[t] = (idx < NN) ? cursor[idx] : 0;
    __syncthreads();
    for (int off = 1; off < SCHUNK; off <<= 1) {
        int v = (t >= off) ? l[t - off] : 0;
        __syncthreads();
        l[t] += v;
        __syncthreads();
    }
    int excl = ((t == 0) ? 0 : l[t - 1]) + boffs[blockIdx.x];
    if (idx < NN) {
        row_ptr[idx] = excl;
        cursor[idx] = excl;
    }
    if (idx == 0) row_ptr[NN] = NE;
}

// fill: eidx[cursor[dst[e]]++] = src[e]
__global__ void csr_fill(const int* __restrict__ src, const int* __restrict__ dst,
                         int* __restrict__ cursor, int* __restrict__ eidx) {
    int e = blockIdx.x * blockDim.x + threadIdx.x;
    if (e >= NE) return;
    int pos = atomicAdd(&cursor[dst[e]], 1);
    eidx[pos] = src[e];
}

// ---------------- gather-aggregate: agg[n][f] = sum_{s in N(n)} x[s][f] -----
// one wave per node; 4 groups of 16 lanes; each group processes one edge with
// float4 row loads -> 4x memory parallelism
template <int F>
__global__ void gather_agg(const int* __restrict__ row_ptr, const int* __restrict__ eidx,
                           const float* __restrict__ x, float* __restrict__ agg) {
    int t = blockIdx.x * blockDim.x + threadIdx.x;
    int n = t >> 6;
    int lane = threadIdx.x & 63;
    if (n >= NN) return;
    int g = lane >> 4;          // group 0..3
    int fl = (lane & 15) * 4;   // feature base for this lane
    int beg = row_ptr[n];
    int end = row_ptr[n + 1];
    float4 acc = make_float4(0.f, 0.f, 0.f, 0.f);
    for (int j0 = beg; j0 < end; j0 += 64) {
        int cnt = min(64, end - j0);
        int myid = (j0 + lane < end) ? eidx[j0 + lane] : 0;
        int steps = (cnt + 3) >> 2;
        for (int u = 0; u < steps; u++) {
            int e = u * 4 + g;
            int s = __shfl(myid, e);
            if (e < cnt && fl < F) {
                const float4 v = *(const float4*)&x[(size_t)s * F + fl];
                acc.x += v.x; acc.y += v.y; acc.z += v.z; acc.w += v.w;
            }
        }
    }
    // reduce across the 4 groups
#pragma unroll
    for (int m = 16; m <= 32; m <<= 1) {
        acc.x += __shfl_xor(acc.x, m);
        acc.y += __shfl_xor(acc.y, m);
        acc.z += __shfl_xor(acc.z, m);
        acc.w += __shfl_xor(acc.w, m);
    }
    if (lane < 16 && fl < F) {
        *(float4*)&agg[(size_t)n * F + fl] = acc;
    }
}

// ---------------- h[n][:] = (agg[n]/max(deg,1)) @ Wl + b + x[n] @ Wr --------
template <int FIN>
__global__ void sage_linear(const float* __restrict__ x, const float* __restrict__ agg,
                            const int* __restrict__ row_ptr,
                            const float* __restrict__ Wl, const float* __restrict__ Wr,
                            const float* __restrict__ b, float* __restrict__ h) {
    int n = blockIdx.x * blockDim.x + threadIdx.x;
    if (n >= NN) return;
    float acc[HID];
#pragma unroll
    for (int j = 0; j < HID; j++) acc[j] = b[j];
    int deg = row_ptr[n + 1] - row_ptr[n];
    float inv = 1.0f / (float)max(deg, 1);
    for (int k = 0; k < FIN; k++) {
        float xa = agg[n * FIN + k] * inv;
        float xr = x[n * FIN + k];
        const float* wl = &Wl[k * HID];
        const float* wr = &Wr[k * HID];
#pragma unroll
        for (int j = 0; j < HID; j++) {
            acc[j] = fmaf(xa, wl[j], fmaf(xr, wr[j], acc[j]));
        }
    }
#pragma unroll
    for (int j = 0; j < HID; j++) h[n * HID + j] = acc[j];
}

// ---------------- BN stats: stats[f] = sum, stats[64+f] = sumsq -------------
__global__ void bn_stats(const float* __restrict__ h, float* __restrict__ stats) {
    const int NPB = 512;
    int f = threadIdx.x & 63;
    int r = threadIdx.x >> 6;
    int n0 = blockIdx.x * NPB;
    int nend = min(n0 + NPB, NN);
    float s = 0.f, ss = 0.f;
    for (int n = n0 + r; n < nend; n += 4) {
        float v = h[n * HID + f];
        s += v;
        ss += v * v;
    }
    __shared__ float ls[4][64];
    __shared__ float lss[4][64];
    ls[r][f] = s;
    lss[r][f] = ss;
    __syncthreads();
    if (r == 0) {
        s = ls[0][f] + ls[1][f] + ls[2][f] + ls[3][f];
        ss = lss[0][f] + lss[1][f] + lss[2][f] + lss[3][f];
        atomicAdd(&stats[f], s);
        atomicAdd(&stats[64 + f], ss);
    }
}

// ---------------- BN apply + ReLU (layer 1 only) ----------------
__global__ void bn_apply_relu(const float* __restrict__ h, const float* __restrict__ stats,
                              const float* __restrict__ g, const float* __restrict__ be,
                              float* __restrict__ x) {
    int idx = blockIdx.x * blockDim.x + threadIdx.x;
    if (idx >= NN * HID) return;
    int f = idx & 63;
    const float invn = 1.0f / (float)NN;
    float m = stats[f] * invn;
    float var = stats[64 + f] * invn - m * m;
    float sc = g[f] / sqrtf(var + EPS);
    float v = (h[idx] - m) * sc + be[f];
    x[idx] = fmaxf(v, 0.0f);
}

// ---------------- graph boundaries from sorted batch ----------------
__global__ void graph_bounds(const int* __restrict__ batch, int* __restrict__ gstart) {
    int n = blockIdx.x * blockDim.x + threadIdx.x;
    if (n >= NN) return;
    int cur = batch[n];
    int prev = (n == 0) ? -1 : batch[n - 1];
    for (int g = prev + 1; g <= cur; g++) gstart[g] = n;
    if (n == NN - 1) {
        for (int g = cur + 1; g <= NG; g++) gstart[g] = NN;
    }
}

// ---------------- fused layer2-BN+ReLU + mean-pool + output GEMV ------------
// one wave per graph; lane = feature
__global__ void pool_out(const float* __restrict__ h, const float* __restrict__ stats2,
                         const float* __restrict__ g2, const float* __restrict__ be2,
                         const int* __restrict__ gstart,
                         const float* __restrict__ Wout, const float* __restrict__ bout,
                         float* __restrict__ out) {
    int w = (blockIdx.x * blockDim.x + threadIdx.x) >> 6;
    int f = threadIdx.x & 63;
    if (w >= NG) return;
    const float invn = 1.0f / (float)NN;
    float m = stats2[f] * invn;
    float var = stats2[64 + f] * invn - m * m;
    float sc = g2[f] / sqrtf(var + EPS);
    float bb = be2[f];
    int n0 = gstart[w], n1 = gstart[w + 1];
    float acc = 0.f;
    for (int n = n0; n < n1; n++) {
        float v = (h[(size_t)n * HID + f] - m) * sc + bb;
        acc += fmaxf(v, 0.0f);
    }
    float inv = 1.0f / (float)max(n1 - n0, 1);
    float p = acc * inv;
    float a0 = p * Wout[f * 2 + 0];
    float a1 = p * Wout[f * 2 + 1];
#pragma unroll
    for (int mm = 1; mm < 64; mm <<= 1) {
        a0 += __shfl_xor(a0, mm);
        a1 += __shfl_xor(a1, mm);
    }
    if (f == 0) {
        out[w * 2 + 0] = a0 + bout[0];
        out[w * 2 + 1] = a1 + bout[1];
    }
}

extern "C" void kernel_launch(void* const* d_in, const int* in_sizes, int n_in,
                              void* d_out, int out_size, void* d_ws, size_t ws_size,
                              hipStream_t stream) {
    const int* sid = (const int*)d_in[0];
    const int* cid = (const int*)d_in[1];
    const int* pid = (const int*)d_in[2];
    const int* ei = (const int*)d_in[3];
    const int* batch = (const int*)d_in[4];
    const float* stab = (const float*)d_in[6];
    const float* ctab = (const float*)d_in[7];
    const float* ptab = (const float*)d_in[8];
    const float* W1l = (const float*)d_in[9];
    const float* b1 = (const float*)d_in[10];
    const float* W1r = (const float*)d_in[11];
    const float* g1 = (const float*)d_in[12];
    const float* be1 = (const float*)d_in[13];
    const float* W2l = (const float*)d_in[14];
    const float* b2 = (const float*)d_in[15];
    const float* W2r = (const float*)d_in[16];
    const float* g2 = (const float*)d_in[17];
    const float* be2 = (const float*)d_in[18];
    const float* Wout = (const float*)d_in[19];
    const float* bout = (const float*)d_in[20];

    const int* src = ei;
    const int* dst = ei + NE;

    float* ws = (float*)d_ws;
    float* x0 = ws;                                // NN*40 f
    float* agg = x0 + (size_t)NN * FIN1;           // NN*64 f
    float* hbuf = agg + (size_t)NN * HID;          // NN*64 f
    float* stats = hbuf + (size_t)NN * HID;        // 256 f (both layers)
    int* row_ptr = (int*)(stats + 256);            // NN+1 i
    int* cursor = row_ptr + NN + 1;                // NN i
    int* bsum = cursor + NN;                       // 256 i
    int* boffs = bsum + 256;                       // 256 i
    int* gstart = boffs + 256;                     // NG+1 i
    int* eidx = gstart + NG + 1;                   // NE i

    hipMemsetAsync(cursor, 0, NN * sizeof(int), stream);
    hipMemsetAsync(stats, 0, 256 * sizeof(float), stream);

    const int B = 256;
    // features
    embed_kernel<<<(NN * FIN1 + B - 1) / B, B, 0, stream>>>(sid, cid, pid, stab, ctab, ptab, x0);

    // CSR build (shared across both layers)
    deg_hist<<<(NE + B - 1) / B, B, 0, stream>>>(dst, cursor);
    scan_a<<<SNB, SCHUNK, 0, stream>>>(cursor, bsum);
    scan_b<<<1, 256, 0, stream>>>(bsum, boffs);
    scan_c<<<SNB, SCHUNK, 0, stream>>>(cursor, boffs, row_ptr);
    csr_fill<<<(NE + B - 1) / B, B, 0, stream>>>(src, dst, cursor, eidx);

    // graph boundaries (independent; any time before pool_out)
    graph_bounds<<<(NN + B - 1) / B, B, 0, stream>>>(batch, gstart);

    // ---- layer 1 ----
    gather_agg<FIN1><<<(NN * 64 + B - 1) / B, B, 0, stream>>>(row_ptr, eidx, x0, agg);
    sage_linear<FIN1><<<(NN + B - 1) / B, B, 0, stream>>>(x0, agg, row_ptr, W1l, W1r, b1, hbuf);
    bn_stats<<<(NN + 511) / 512, B, 0, stream>>>(hbuf, stats);
    bn_apply_relu<<<(NN * HID + B - 1) / B, B, 0, stream>>>(hbuf, stats, g1, be1, hbuf);

    // ---- layer 2 ----
    gather_agg<HID><<<(NN * 64 + B - 1) / B, B, 0, stream>>>(row_ptr, eidx, hbuf, agg);
    sage_linear<HID><<<(NN + B - 1) / B, B, 0, stream>>>(hbuf, agg, row_ptr, W2l, W2r, b2, hbuf);
    bn_stats<<<(NN + 511) / 512, B, 0, stream>>>(hbuf, stats + 128);

    // ---- fused BN2+ReLU+pool+head ----
    pool_out<<<(NG * 64 + B - 1) / B, B, 0, stream>>>(hbuf, stats + 128, g2, be2, gstart,
                                                      Wout, bout, (float*)d_out);
}